// Round 10
// baseline (795.101 us; speedup 1.0000x reference)
//
#include <hip/hip_runtime.h>
#include <hip/hip_bf16.h>

// B=512, A=4, D=6, N=1365, E=128. Level starts {0,1,5,21,85,341}.
// One block per batch tree, 512 thr (8 waves). LDS 79.2 KB -> TARGET 2 blocks/CU.
// R8 structure (best: 78.8 us): 24 phases, one barrier each, depth-2 gather
// pipeline (RA/RB regs -> bf16 dbuf Xe), Wc frags VGPR-resident.
// R10 change: Ws LDS copy evicted (-35 KB); the 6 dual-chain phases load Ws
// fragments transiently from global (L2-hot, same addresses each time), with
// the dual kb-loop kept ROLLED so transients stay ~16 regs (no spill).
// Pure function of d_in: no workspace, no atomics, no memset.
#define NTOK 1365
#define ED   128
#define STR  136   // bf16 LDS row stride: 272 B, 16B-aligned, balanced banks

typedef __attribute__((ext_vector_type(8))) short short8;
typedef __attribute__((ext_vector_type(4))) float f32x4;

#define MFMA(a,b,c) __builtin_amdgcn_mfma_f32_16x16x32_bf16((a),(b),(c),0,0,0)

__device__ __forceinline__ ushort f2bf(float f) {  // round-to-nearest-even
  union { float f; unsigned u; } v; v.f = f;
  unsigned r = v.u + 0x7fffu + ((v.u >> 16) & 1u);
  return (ushort)(r >> 16);
}
__device__ __forceinline__ ushort4 cvt4(float4 f) {
  ushort4 u; u.x = f2bf(f.x); u.y = f2bf(f.y); u.z = f2bf(f.z); u.w = f2bf(f.w);
  return u;
}
__device__ __forceinline__ short8 pack8(float4 a, float4 b) {
  union { ushort us[8]; short8 s8; } t;
  t.us[0]=f2bf(a.x); t.us[1]=f2bf(a.y); t.us[2]=f2bf(a.z); t.us[3]=f2bf(a.w);
  t.us[4]=f2bf(b.x); t.us[5]=f2bf(b.y); t.us[6]=f2bf(b.z); t.us[7]=f2bf(b.w);
  return t.s8;
}

// LDS: PM 1024 floats (4096 B) + bf16 rows: Xe0 64, Xe1 64, CS4 64, CS3 64,
// CS2 16, CS1 4 = 276 rows * 272 B = 75072 B. Total 79168 B -> 2 blocks/CU.
#define SM_BYTES (4096 + 276 * STR * 2)

__global__ __attribute__((amdgpu_flat_work_group_size(512, 512),
                          amdgpu_waves_per_eu(2, 8)))
void tree_kernel(
    const int* __restrict__ tokens, const float* __restrict__ emb,
    const float* __restrict__ WcW,  const float* __restrict__ Wcb,
    const float* __restrict__ WsW,  const float* __restrict__ Wsb,
    float* __restrict__ out) {
  extern __shared__ char smem[];
  float*  PM  = (float*)smem;            // [8][128] per-wave col maxima
  ushort* Xe0 = (ushort*)(PM + 1024);    // staging buf 0 (64 rows, bf16)
  ushort* Xe1 = Xe0 + 64*STR;            // staging buf 1
  ushort* CS4 = Xe1 + 64*STR;            // leaf child-sums, 64 rows (per quarter)
  ushort* CS3 = CS4 + 64*STR;            // 64 rows (= L3 node idx)
  ushort* CS2 = CS3 + 64*STR;            // 16 rows; row 0 reused as H1
  ushort* CS1 = CS2 + 16*STR;            // 4 rows

  const int  tid = threadIdx.x;
  const int  b   = blockIdx.x;
  const long tokbase = (long)b * NTOK;
  const int  w    = tid >> 6;            // wave 0..7
  const int  lane = tid & 63;
  const int  n16  = lane & 15;
  const int  quad = lane >> 4;
  const int  mtg  = w >> 2, ntg = w & 3; // 2x4 wave grid for M=64 phases
  const int  kof  = quad * 8;

  // ---- biases in registers (all phases share the column mapping) ----
  float bcv[2], bsv[2];
  #pragma unroll
  for (int j = 0; j < 2; j++) {
    const int c = ntg*32 + j*16 + n16;
    bcv[j] = Wcb[c]; bsv[j] = 4.f * Wsb[c];
  }

  // ---- Wc fragments resident in VGPRs (hot: every phase, 32 regs) ----
  short8 Bc[2][4];
  #pragma unroll
  for (int jt = 0; jt < 2; jt++)
    #pragma unroll
    for (int kb = 0; kb < 4; kb++) {
      const float* pc = WcW + (ntg*32 + jt*16 + n16)*ED + kb*32 + kof;
      Bc[jt][kb] = pack8(((const float4*)pc)[0], ((const float4*)pc)[1]);
    }

  for (int i = tid; i < 1024; i += 512) PM[i] = 0.f;

  float pm[2] = {0.f, 0.f};              // relu floor, cols ntg*32+j*16+n16

  // ---- Ws fragment from global (L2-hot; transient regs) ----
  auto bsfrag = [&](int jt, int kb) -> short8 {
    const float* ps = WsW + (ntg*32 + jt*16 + n16)*ED + kb*32 + kof;
    return pack8(((const float4*)ps)[0], ((const float4*)ps)[1]);
  };

  // ---- depth-2 pipelined gathers: two named register sets ----
  float4 RA[4], RB[4];
  auto issue64 = [&](float4 (&R)[4], int ofs) {   // 64 rows, 8 thr/row
    const int r = tid >> 3, p = tid & 7;
    const float4* src = (const float4*)(emb + (long)tokens[tokbase + ofs + r]*ED) + (p << 2);
    R[0] = src[0]; R[1] = src[1]; R[2] = src[2]; R[3] = src[3];
  };
  auto store64 = [&](const float4 (&R)[4], ushort* Xe) {
    const int r = tid >> 3, p = tid & 7;
    short8* d = (short8*)(Xe + r*STR + (p << 4));
    d[0] = pack8(R[0], R[1]); d[1] = pack8(R[2], R[3]);
  };
  auto issueN = [&](float4 (&R)[4], int ofs, int nrows) { // 32 thr/row
    const int r = tid >> 5, p = tid & 31;
    if (r < nrows) R[0] = ((const float4*)(emb + (long)tokens[tokbase + ofs + r]*ED))[p];
  };
  auto storeN = [&](const float4 (&R)[4], ushort* Xe, int nrows) {
    const int r = tid >> 5, p = tid & 31;
    if (r < nrows) *(ushort4*)(Xe + r*STR + (p << 2)) = cvt4(R[0]);
  };

  // ---- leaf M=64 phase: acc = Xe@Wc^T; relu-max + child-quad-sums ----
  auto phase64 = [&](const ushort* Xe, ushort* csdst, int csrow0) {
    f32x4 acc[2][2];
    #pragma unroll
    for (int i = 0; i < 2; i++)
      #pragma unroll
      for (int j = 0; j < 2; j++) acc[i][j] = (f32x4){0.f,0.f,0.f,0.f};
    #pragma unroll
    for (int kb = 0; kb < 4; kb++) {
      const int ko = kb*32 + kof;
      short8 a0 = *(const short8*)(Xe + (mtg*32      + n16)*STR + ko);
      short8 a1 = *(const short8*)(Xe + (mtg*32 + 16 + n16)*STR + ko);
      acc[0][0]=MFMA(a0,Bc[0][kb],acc[0][0]); acc[0][1]=MFMA(a0,Bc[1][kb],acc[0][1]);
      acc[1][0]=MFMA(a1,Bc[0][kb],acc[1][0]); acc[1][1]=MFMA(a1,Bc[1][kb],acc[1][1]);
    }
    #pragma unroll
    for (int i = 0; i < 2; i++) {
      const int p = mtg*8 + i*4 + quad;          // C row / 4 = parent idx
      #pragma unroll
      for (int j = 0; j < 2; j++) {
        f32x4 A = acc[i][j];
        const float bb = bcv[j];
        float h0=A[0]+bb, h1=A[1]+bb, h2=A[2]+bb, h3=A[3]+bb;
        pm[j] = fmaxf(pm[j], fmaxf(fmaxf(h0,h1), fmaxf(h2,h3)));
        csdst[(csrow0 + p)*STR + ntg*32 + j*16 + n16] =
            f2bf(A[0]+A[1]+A[2]+A[3] + 4.f*bb);
      }
    }
  };

  // ---- dual M=64 phase: + csrc@Ws^T, Ws from global; kb loop ROLLED so the
  //      16 transient Ws regs don't unroll into a spill ----
  auto phase64d = [&](const ushort* Xe, const ushort* csrc, ushort* csdst, int csrow0) {
    f32x4 acc[2][2];
    #pragma unroll
    for (int i = 0; i < 2; i++)
      #pragma unroll
      for (int j = 0; j < 2; j++) acc[i][j] = (f32x4){0.f,0.f,0.f,0.f};
    #pragma unroll 1
    for (int kb = 0; kb < 4; kb++) {
      const int ko = kb*32 + kof;
      short8 s0 = bsfrag(0, kb);
      short8 s1 = bsfrag(1, kb);
      short8 a0 = *(const short8*)(Xe + (mtg*32      + n16)*STR + ko);
      short8 a1 = *(const short8*)(Xe + (mtg*32 + 16 + n16)*STR + ko);
      short8 c0 = *(const short8*)(csrc + (mtg*32      + n16)*STR + ko);
      short8 c1 = *(const short8*)(csrc + (mtg*32 + 16 + n16)*STR + ko);
      acc[0][0]=MFMA(a0,Bc[0][kb],acc[0][0]); acc[0][1]=MFMA(a0,Bc[1][kb],acc[0][1]);
      acc[1][0]=MFMA(a1,Bc[0][kb],acc[1][0]); acc[1][1]=MFMA(a1,Bc[1][kb],acc[1][1]);
      acc[0][0]=MFMA(c0,s0,acc[0][0]); acc[0][1]=MFMA(c0,s1,acc[0][1]);
      acc[1][0]=MFMA(c1,s0,acc[1][0]); acc[1][1]=MFMA(c1,s1,acc[1][1]);
    }
    #pragma unroll
    for (int i = 0; i < 2; i++) {
      const int p = mtg*8 + i*4 + quad;
      #pragma unroll
      for (int j = 0; j < 2; j++) {
        const float bb = bcv[j] + bsv[j];
        f32x4 A = acc[i][j];
        float h0=A[0]+bb, h1=A[1]+bb, h2=A[2]+bb, h3=A[3]+bb;
        pm[j] = fmaxf(pm[j], fmaxf(fmaxf(h0,h1), fmaxf(h2,h3)));
        csdst[(csrow0 + p)*STR + ntg*32 + j*16 + n16] =
            f2bf(A[0]+A[1]+A[2]+A[3] + 4.f*bb);
      }
    }
  };

  // ---- small phases (mtg==0 waves only), Ws from global ----
  auto smallphase = [&](const ushort* Xe, const ushort* csrc, int M, ushort* csdst) {
    if (mtg != 0) return;
    const int ar = (M == 16) ? n16 : ((M == 4) ? (n16 & 3) : 0);  // row clamp
    f32x4 acc[2];
    acc[0] = (f32x4){0.f,0.f,0.f,0.f}; acc[1] = (f32x4){0.f,0.f,0.f,0.f};
    #pragma unroll 1
    for (int kb = 0; kb < 4; kb++) {
      const int ko = kb*32 + kof;
      short8 s0 = bsfrag(0, kb);
      short8 s1 = bsfrag(1, kb);
      short8 a  = *(const short8*)(Xe   + ar*STR + ko);
      short8 c2 = *(const short8*)(csrc + ar*STR + ko);
      acc[0] = MFMA(a,  Bc[0][kb], acc[0]); acc[1] = MFMA(a,  Bc[1][kb], acc[1]);
      acc[0] = MFMA(c2, s0, acc[0]);        acc[1] = MFMA(c2, s1, acc[1]);
    }
    #pragma unroll
    for (int j = 0; j < 2; j++) {
      const float bb = bcv[j] + bsv[j];
      f32x4 A = acc[j];
      const int c = ntg*32 + j*16 + n16;
      if (M == 16) {
        float h0=A[0]+bb, h1=A[1]+bb, h2=A[2]+bb, h3=A[3]+bb;
        pm[j] = fmaxf(pm[j], fmaxf(fmaxf(h0,h1), fmaxf(h2,h3)));
        csdst[quad*STR + c] = f2bf(A[0]+A[1]+A[2]+A[3] + 4.f*bb);
      } else if (M == 4) {
        if (quad == 0) {
          float h0=A[0]+bb, h1=A[1]+bb, h2=A[2]+bb, h3=A[3]+bb;
          pm[j] = fmaxf(pm[j], fmaxf(fmaxf(h0,h1), fmaxf(h2,h3)));
          csdst[c] = f2bf(A[0]+A[1]+A[2]+A[3] + 4.f*bb);   // H1 = sum of 4 h1
        }
      } else {
        if (quad == 0) pm[j] = fmaxf(pm[j], A[0] + bb);    // root h0
      }
    }
  };

  // ---- explicit 24-phase driver (R8): phase n computes Xe(n&1); gather for
  //      n+2 issues into RA/RB (parity n&1); n+1's regs store into Xe((n+1)&1).
  issue64(RA, 341);                  // leaf(0,0)
  issue64(RB, 341 + 64);             // leaf(0,1)
  store64(RA, Xe0);
  __syncthreads();
  /*n=0 leaf(0,0)*/ issue64(RA, 341+128);     phase64(Xe0, CS4,  0);           store64(RB, Xe1); __syncthreads();
  /*n=1 leaf(0,1)*/ issue64(RB, 341+192);     phase64(Xe1, CS4, 16);           store64(RA, Xe0); __syncthreads();
  /*n=2 leaf(0,2)*/ issue64(RA, 85);          phase64(Xe0, CS4, 32);           store64(RB, Xe1); __syncthreads();
  /*n=3 leaf(0,3)*/ issue64(RB, 341+256);     phase64(Xe1, CS4, 48);           store64(RA, Xe0); __syncthreads();
  /*n=4 L4 q0   */ issue64(RA, 341+256+64);   phase64d(Xe0, CS4, CS3,  0);     store64(RB, Xe1); __syncthreads();
  /*n=5 leaf(1,0)*/ issue64(RB, 341+256+128); phase64(Xe1, CS4,  0);           store64(RA, Xe0); __syncthreads();
  /*n=6 leaf(1,1)*/ issue64(RA, 341+256+192); phase64(Xe0, CS4, 16);           store64(RB, Xe1); __syncthreads();
  /*n=7 leaf(1,2)*/ issue64(RB, 85+64);       phase64(Xe1, CS4, 32);           store64(RA, Xe0); __syncthreads();
  /*n=8 leaf(1,3)*/ issue64(RA, 341+512);     phase64(Xe0, CS4, 48);           store64(RB, Xe1); __syncthreads();
  /*n=9 L4 q1   */ issue64(RB, 341+512+64);   phase64d(Xe1, CS4, CS3, 16);     store64(RA, Xe0); __syncthreads();
  /*n=10 leaf(2,0)*/ issue64(RA, 341+512+128); phase64(Xe0, CS4,  0);          store64(RB, Xe1); __syncthreads();
  /*n=11 leaf(2,1)*/ issue64(RB, 341+512+192); phase64(Xe1, CS4, 16);          store64(RA, Xe0); __syncthreads();
  /*n=12 leaf(2,2)*/ issue64(RA, 85+128);      phase64(Xe0, CS4, 32);          store64(RB, Xe1); __syncthreads();
  /*n=13 leaf(2,3)*/ issue64(RB, 341+768);     phase64(Xe1, CS4, 48);          store64(RA, Xe0); __syncthreads();
  /*n=14 L4 q2   */ issue64(RA, 341+768+64);   phase64d(Xe0, CS4, CS3, 32);    store64(RB, Xe1); __syncthreads();
  /*n=15 leaf(3,0)*/ issue64(RB, 341+768+128); phase64(Xe1, CS4,  0);          store64(RA, Xe0); __syncthreads();
  /*n=16 leaf(3,1)*/ issue64(RA, 341+768+192); phase64(Xe0, CS4, 16);          store64(RB, Xe1); __syncthreads();
  /*n=17 leaf(3,2)*/ issue64(RB, 85+192);      phase64(Xe1, CS4, 32);          store64(RA, Xe0); __syncthreads();
  /*n=18 leaf(3,3)*/ issue64(RA, 21);          phase64(Xe0, CS4, 48);          store64(RB, Xe1); __syncthreads();
  /*n=19 L4 q3   */ issueN(RB, 5, 16);         phase64d(Xe1, CS4, CS3, 48);    store64(RA, Xe0); __syncthreads();
  /*n=20 L3 dual */ issueN(RA, 1, 4);          phase64d(Xe0, CS3, CS2,  0);    storeN(RB, Xe1, 16); __syncthreads();
  /*n=21 L2 M=16 */ issueN(RB, 0, 1);          smallphase(Xe1, CS2, 16, CS1);  storeN(RA, Xe0, 4);  __syncthreads();
  /*n=22 L1 M=4  */                            smallphase(Xe0, CS1, 4,  CS2);  storeN(RB, Xe1, 1);  __syncthreads();
  /*n=23 root    */                            smallphase(Xe1, CS2, 1,  nullptr);

  // ---- merge per-lane maxima -> PM -> out ----
  #pragma unroll
  for (int j = 0; j < 2; j++) {
    float v = pm[j];
    v = fmaxf(v, __shfl_xor(v, 16, 64));
    v = fmaxf(v, __shfl_xor(v, 32, 64));
    if (quad == 0) PM[w*128 + ntg*32 + j*16 + n16] = v;
  }
  __syncthreads();
  if (tid < 128) {
    float m = 0.f;
    #pragma unroll
    for (int r = 0; r < 8; r++) m = fmaxf(m, PM[r*128 + tid]);
    out[(long)b*ED + tid] = m;
  }
}

extern "C" void kernel_launch(void* const* d_in, const int* in_sizes, int n_in,
                              void* d_out, int out_size, void* d_ws, size_t ws_size,
                              hipStream_t stream) {
  const int*   tokens = (const int*)d_in[0];
  const float* emb    = (const float*)d_in[1];
  const float* WcW    = (const float*)d_in[2];
  const float* Wcb    = (const float*)d_in[3];
  const float* WsW    = (const float*)d_in[4];
  const float* Wsb    = (const float*)d_in[5];
  float* out = (float*)d_out;
  (void)d_ws; (void)ws_size;

  hipFuncSetAttribute(reinterpret_cast<const void*>(tree_kernel),
                      hipFuncAttributeMaxDynamicSharedMemorySize, SM_BYTES);
  tree_kernel<<<512, 512, SM_BYTES, stream>>>(tokens, emb, WcW, Wcb, WsW, Wsb, out);
}

// Round 13
// 183.728 us; speedup vs baseline: 4.3276x; 4.3276x over previous
//
#include <hip/hip_runtime.h>
#include <hip/hip_bf16.h>

// B=512, A=4, D=6, N=1365, E=128. Level starts {0,1,5,21,85,341}.
// R13 = R12 with (1) DMA switched to the R9-hardware-validated SIZE-16
// global_load_lds form: lanes 0-31 carry row 2p, lanes 32-63 row 2p+1
// (per-lane token/addr), dest = pair_base + lane*16; (2) staging pair stride
// 268 floats -> even-lane start banks {0,12,24,4,16,28,8,20} (8 distinct),
// only the structural even/odd 2-way alias remains; (3) final reduce reads
// only the 2 valid PM rows per column (stale-overlay bug fixed).
// TWO trees per block (grid 256, 512 thr): per slot the block DMAs the OTHER
// tree's next tile while computing this tree's phase; the barrier drains a
// DMA that had a full compute phase to land. Wc AND Ws fragments
// VGPR-resident (~100 regs, no staging regs, no spill). Pure function of d_in.
#define NTOK 1365
#define ED   128
#define PPB  268   // floats per staged ROW-PAIR (2*128 + 12 pad); 16B-aligned
#define STR  136   // bf16 CS row stride (ushorts) = 272 B

typedef __attribute__((ext_vector_type(8))) short short8;
typedef __attribute__((ext_vector_type(4))) float f32x4;

#define MFMA(a,b,c) __builtin_amdgcn_mfma_f32_16x16x32_bf16((a),(b),(c),0,0,0)

__device__ __forceinline__ ushort f2bf(float f) {  // round-to-nearest-even
  union { float f; unsigned u; } v; v.f = f;
  unsigned r = v.u + 0x7fffu + ((v.u >> 16) & 1u);
  return (ushort)(r >> 16);
}
__device__ __forceinline__ short8 pack8(float4 a, float4 b) {
  union { ushort us[8]; short8 s8; } t;
  t.us[0]=f2bf(a.x); t.us[1]=f2bf(a.y); t.us[2]=f2bf(a.z); t.us[3]=f2bf(a.w);
  t.us[4]=f2bf(b.x); t.us[5]=f2bf(b.y); t.us[6]=f2bf(b.z); t.us[7]=f2bf(b.w);
  return t.s8;
}

typedef __attribute__((address_space(3))) unsigned       lds_u32;
typedef __attribute__((address_space(1))) const unsigned gbl_u32;
__device__ __forceinline__ void load_lds16(const void* g_lane, void* l_base) {
  // per-lane 16 B from g_lane; LDS dest = l_base + lane*16 (R9-validated)
  __builtin_amdgcn_global_load_lds((gbl_u32*)g_lane, (lds_u32*)l_base, 16, 0, 0);
}

// LDS: Xf[2] = 32 pairs * PPB floats each (34304 B), per-tree CS block
// 148 rows bf16 (40256 B). Total 149120 B -> 1 block/CU. PM overlays Xf.
#define SM_BYTES (2*32*PPB*4 + 2*(64+64+16+4)*STR*2)

__global__ __attribute__((amdgpu_flat_work_group_size(512, 512),
                          amdgpu_waves_per_eu(2, 8)))
void tree_kernel(
    const int* __restrict__ tokens, const float* __restrict__ emb,
    const float* __restrict__ WcW,  const float* __restrict__ Wcb,
    const float* __restrict__ WsW,  const float* __restrict__ Wsb,
    float* __restrict__ out) {
  extern __shared__ char smem[];
  float*  Xf0 = (float*)smem;                 // tree0 staging: 32 pairs
  float*  Xf1 = Xf0 + 32*PPB;                 // tree1 staging
  ushort* C0  = (ushort*)(Xf1 + 32*PPB);      // tree0 CS block: 148 rows
  ushort* C1  = C0 + 148*STR;                 // tree1 CS block
  float*  Xf[2]  = {Xf0, Xf1};
  ushort* CS4[2] = {C0,            C1};
  ushort* CS3[2] = {C0 + 64*STR,   C1 + 64*STR};
  ushort* CS2[2] = {C0 + 128*STR,  C1 + 128*STR};   // row 0 reused as H1
  ushort* CS1[2] = {C0 + 144*STR,  C1 + 144*STR};

  const int  tid = threadIdx.x;
  const int  b   = blockIdx.x;                // 0..255; trees 2b, 2b+1
  const long tokbase[2] = {(long)(2*b)*NTOK, (long)(2*b+1)*NTOK};
  const int  w    = tid >> 6;                 // wave 0..7
  const int  lane = tid & 63;
  const int  n16  = lane & 15;
  const int  quad = lane >> 4;
  const int  mtg  = w >> 2, ntg = w & 3;      // 2x4 wave grid for M=64 phases
  const int  kof  = quad * 8;                 // k offset (elements)
  const int  rpar = lane >> 5;                // DMA row parity (0: lanes 0-31)
  const int  chnk = lane & 31;                // DMA 16B chunk within row

  // ---- biases + resident Wc/Ws fragments (64 VGPRs) ----
  float bcv[2], bsv[2];
  #pragma unroll
  for (int j = 0; j < 2; j++) {
    const int c = ntg*32 + j*16 + n16;
    bcv[j] = Wcb[c]; bsv[j] = 4.f * Wsb[c];
  }
  short8 Bc[2][4], Bs[2][4];
  #pragma unroll
  for (int jt = 0; jt < 2; jt++)
    #pragma unroll
    for (int kb = 0; kb < 4; kb++) {
      const float* pc = WcW + (ntg*32 + jt*16 + n16)*ED + kb*32 + kof;
      Bc[jt][kb] = pack8(((const float4*)pc)[0], ((const float4*)pc)[1]);
      const float* ps = WsW + (ntg*32 + jt*16 + n16)*ED + kb*32 + kof;
      Bs[jt][kb] = pack8(((const float4*)ps)[0], ((const float4*)ps)[1]);
    }

  float pm[4] = {0.f, 0.f, 0.f, 0.f};         // [tree*2 + j] relu-floor maxima

  // ---- DMA issue (size-16, R9 form): pair pi holds rows 2pi, 2pi+1 ----
  auto dma64 = [&](int t, int ofs) {          // 64 rows = 32 pairs; 4 pairs/wave
    #pragma unroll
    for (int tt = 0; tt < 4; tt++) {
      const int pi = w*4 + tt;
      const int r  = 2*pi + rpar;             // per-lane row
      const long tok = tokens[tokbase[t] + ofs + r];
      const float* g = emb + tok*ED + chnk*4; // lane's own 16 B
      load_lds16(g, Xf[t] + pi*PPB);          // lane*16 spans the 1024-B pair
    }
  };
  auto dmaS = [&](int t, int ofs, int nrows) { // nrows in {16,4,1}; stage pairs
    const int npair = (nrows + 1) >> 1;        // 8 / 2 / 1
    if (w < npair) {
      const int r = 2*w + rpar;                // row 1 junk-but-valid for nrows=1
      const long tok = tokens[tokbase[t] + ofs + r];
      const float* g = emb + tok*ED + chnk*4;
      load_lds16(g, Xf[t] + w*PPB);
    }
  };

  // ---- A-fragment: fp32 LDS pair-row -> bf16 short8 at use ----
  auto afrag = [&](int t, int r, int kb) -> short8 {
    const float* p = Xf[t] + (r >> 1)*PPB + (r & 1)*128 + kb*32 + kof;
    return pack8(((const float4*)p)[0], ((const float4*)p)[1]);
  };

  // ---- leaf M=64 phase ----
  auto phaseL = [&](int t, int csrow0) {
    f32x4 acc[2][2];
    #pragma unroll
    for (int i = 0; i < 2; i++)
      #pragma unroll
      for (int j = 0; j < 2; j++) acc[i][j] = (f32x4){0.f,0.f,0.f,0.f};
    #pragma unroll
    for (int kb = 0; kb < 4; kb++) {
      short8 a0 = afrag(t, mtg*32      + n16, kb);
      short8 a1 = afrag(t, mtg*32 + 16 + n16, kb);
      acc[0][0]=MFMA(a0,Bc[0][kb],acc[0][0]); acc[0][1]=MFMA(a0,Bc[1][kb],acc[0][1]);
      acc[1][0]=MFMA(a1,Bc[0][kb],acc[1][0]); acc[1][1]=MFMA(a1,Bc[1][kb],acc[1][1]);
    }
    #pragma unroll
    for (int i = 0; i < 2; i++) {
      const int p = mtg*8 + i*4 + quad;       // C row / 4 = parent idx
      #pragma unroll
      for (int j = 0; j < 2; j++) {
        f32x4 A = acc[i][j];
        const float bb = bcv[j];
        float h0=A[0]+bb, h1=A[1]+bb, h2=A[2]+bb, h3=A[3]+bb;
        pm[t*2+j] = fmaxf(pm[t*2+j], fmaxf(fmaxf(h0,h1), fmaxf(h2,h3)));
        CS4[t][(csrow0 + p)*STR + ntg*32 + j*16 + n16] =
            f2bf(A[0]+A[1]+A[2]+A[3] + 4.f*bb);
      }
    }
  };

  // ---- dual M=64 phase (L4/L3): + csrc@Ws^T ----
  auto phaseD = [&](int t, const ushort* csrc, ushort* csdst, int csrow0) {
    f32x4 acc[2][2];
    #pragma unroll
    for (int i = 0; i < 2; i++)
      #pragma unroll
      for (int j = 0; j < 2; j++) acc[i][j] = (f32x4){0.f,0.f,0.f,0.f};
    #pragma unroll
    for (int kb = 0; kb < 4; kb++) {
      const int ko = kb*32 + kof;
      short8 a0 = afrag(t, mtg*32      + n16, kb);
      short8 a1 = afrag(t, mtg*32 + 16 + n16, kb);
      short8 c0 = *(const short8*)(csrc + (mtg*32      + n16)*STR + ko);
      short8 c1 = *(const short8*)(csrc + (mtg*32 + 16 + n16)*STR + ko);
      acc[0][0]=MFMA(a0,Bc[0][kb],acc[0][0]); acc[0][1]=MFMA(a0,Bc[1][kb],acc[0][1]);
      acc[1][0]=MFMA(a1,Bc[0][kb],acc[1][0]); acc[1][1]=MFMA(a1,Bc[1][kb],acc[1][1]);
      acc[0][0]=MFMA(c0,Bs[0][kb],acc[0][0]); acc[0][1]=MFMA(c0,Bs[1][kb],acc[0][1]);
      acc[1][0]=MFMA(c1,Bs[0][kb],acc[1][0]); acc[1][1]=MFMA(c1,Bs[1][kb],acc[1][1]);
    }
    #pragma unroll
    for (int i = 0; i < 2; i++) {
      const int p = mtg*8 + i*4 + quad;
      #pragma unroll
      for (int j = 0; j < 2; j++) {
        const float bb = bcv[j] + bsv[j];
        f32x4 A = acc[i][j];
        float h0=A[0]+bb, h1=A[1]+bb, h2=A[2]+bb, h3=A[3]+bb;
        pm[t*2+j] = fmaxf(pm[t*2+j], fmaxf(fmaxf(h0,h1), fmaxf(h2,h3)));
        csdst[(csrow0 + p)*STR + ntg*32 + j*16 + n16] =
            f2bf(A[0]+A[1]+A[2]+A[3] + 4.f*bb);
      }
    }
  };

  // ---- small phases (mtg==0 waves only) ----
  auto phaseS = [&](int t, const ushort* csrc, int M, ushort* csdst) {
    if (mtg != 0) return;
    const int ar = (M == 16) ? n16 : ((M == 4) ? (n16 & 3) : 0);  // row clamp
    f32x4 acc[2];
    acc[0] = (f32x4){0.f,0.f,0.f,0.f}; acc[1] = (f32x4){0.f,0.f,0.f,0.f};
    #pragma unroll
    for (int kb = 0; kb < 4; kb++) {
      short8 a  = afrag(t, ar, kb);
      short8 c2 = *(const short8*)(csrc + ar*STR + kb*32 + kof);
      acc[0] = MFMA(a,  Bc[0][kb], acc[0]); acc[1] = MFMA(a,  Bc[1][kb], acc[1]);
      acc[0] = MFMA(c2, Bs[0][kb], acc[0]); acc[1] = MFMA(c2, Bs[1][kb], acc[1]);
    }
    #pragma unroll
    for (int j = 0; j < 2; j++) {
      const float bb = bcv[j] + bsv[j];
      f32x4 A = acc[j];
      const int c = ntg*32 + j*16 + n16;
      if (M == 16) {
        float h0=A[0]+bb, h1=A[1]+bb, h2=A[2]+bb, h3=A[3]+bb;
        pm[t*2+j] = fmaxf(pm[t*2+j], fmaxf(fmaxf(h0,h1), fmaxf(h2,h3)));
        csdst[quad*STR + c] = f2bf(A[0]+A[1]+A[2]+A[3] + 4.f*bb);
      } else if (M == 4) {
        if (quad == 0) {
          float h0=A[0]+bb, h1=A[1]+bb, h2=A[2]+bb, h3=A[3]+bb;
          pm[t*2+j] = fmaxf(pm[t*2+j], fmaxf(fmaxf(h0,h1), fmaxf(h2,h3)));
          csdst[c] = f2bf(A[0]+A[1]+A[2]+A[3] + 4.f*bb);   // H1 = sum of 4 h1
        }
      } else {
        if (quad == 0) pm[t*2+j] = fmaxf(pm[t*2+j], A[0] + bb);  // root h0
      }
    }
  };

  // ---- phase p dispatch ----
  auto issueFor = [&](int t, int p) {
    if (p < 20) {
      const int q = p / 5, g = p % 5;
      dma64(t, (g < 4) ? (341 + q*256 + g*64) : (85 + q*64));
    } else if (p == 20) dma64(t, 21);
    else if (p == 21) dmaS(t, 5, 16);
    else if (p == 22) dmaS(t, 1, 4);
    else              dmaS(t, 0, 1);
  };
  auto computeP = [&](int t, int p) {
    if (p < 20) {
      const int q = p / 5, g = p % 5;
      if (g < 4) phaseL(t, g*16);
      else       phaseD(t, CS4[t], CS3[t], q*16);
    } else if (p == 20) phaseD(t, CS3[t], CS2[t], 0);
    else if (p == 21)   phaseS(t, CS2[t], 16, CS1[t]);
    else if (p == 22)   phaseS(t, CS1[t], 4,  CS2[t]);
    else                phaseS(t, CS2[t], 1,  nullptr);
  };

  // ---- 48-slot driver: slot computes (tree, phase) while the other tree's
  //      next tile DMAs; barrier drains after the overlap. ----
  issueFor(0, 0);
  __syncthreads();
  #pragma unroll
  for (int p = 0; p < 24; p++) {
    issueFor(1, p);                   // overlaps compute(0,p)
    computeP(0, p);
    __syncthreads();
    if (p < 23) issueFor(0, p + 1);   // overlaps compute(1,p)
    computeP(1, p);
    __syncthreads();
  }

  // ---- merge per-lane maxima; PM overlays the (now dead) Xf buffers.
  //      Wave w covers cols (w&3)*32..+31 -> col c valid in rows c>>5, (c>>5)+4.
  float* PMt[2] = {Xf0, Xf1};
  #pragma unroll
  for (int t = 0; t < 2; t++)
    #pragma unroll
    for (int j = 0; j < 2; j++) {
      float v = pm[t*2+j];
      v = fmaxf(v, __shfl_xor(v, 16, 64));
      v = fmaxf(v, __shfl_xor(v, 32, 64));
      if (quad == 0) PMt[t][w*128 + ntg*32 + j*16 + n16] = v;
    }
  __syncthreads();
  if (tid < 128) {
    const int r0 = tid >> 5;          // exact-2-row reduce (no stale reads)
    float m0 = fmaxf(PMt[0][r0*128 + tid], PMt[0][(r0+4)*128 + tid]);
    float m1 = fmaxf(PMt[1][r0*128 + tid], PMt[1][(r0+4)*128 + tid]);
    out[(long)(2*b)*ED + tid]   = m0;
    out[(long)(2*b+1)*ED + tid] = m1;
  }
}

extern "C" void kernel_launch(void* const* d_in, const int* in_sizes, int n_in,
                              void* d_out, int out_size, void* d_ws, size_t ws_size,
                              hipStream_t stream) {
  const int*   tokens = (const int*)d_in[0];
  const float* emb    = (const float*)d_in[1];
  const float* WcW    = (const float*)d_in[2];
  const float* Wcb    = (const float*)d_in[3];
  const float* WsW    = (const float*)d_in[4];
  const float* Wsb    = (const float*)d_in[5];
  float* out = (float*)d_out;
  (void)d_ws; (void)ws_size;

  hipFuncSetAttribute(reinterpret_cast<const void*>(tree_kernel),
                      hipFuncAttributeMaxDynamicSharedMemorySize, SM_BYTES);
  tree_kernel<<<256, 512, SM_BYTES, stream>>>(tokens, emb, WcW, Wcb, WsW, Wsb, out);
}